// Round 5
// baseline (27.265 us; speedup 1.0000x reference)
//
#include <hip/hip_runtime.h>
#include <hip/hip_bf16.h>

#define HOURS 24
#define NB 32
#define MM 128
#define EE 128

typedef short bf16x8 __attribute__((ext_vector_type(8)));
typedef float f32x4 __attribute__((ext_vector_type(4)));

__device__ __forceinline__ unsigned short f2bfu(float f) {
    __hip_bfloat16 h = __float2bfloat16(f);
    return __builtin_bit_cast(unsigned short, h);
}
__device__ __forceinline__ unsigned int pack2(float a, float b) {
    return (unsigned int)f2bfu(a) | ((unsigned int)f2bfu(b) << 16);
}
// swizzled short-index of 16B unit `unit` in row `row` of a [*][128] bf16 tile
__device__ __forceinline__ int swz8(int row, int unit) {
    return row * 128 + (((unit ^ (row & 7)) & 15) << 3);
}
// load 8 consecutive f32 from global, convert to bf16x8 fragment
__device__ __forceinline__ bf16x8 load_w_frag(const float* base) {
    float4 x = *(const float4*)base;
    float4 y = *(const float4*)(base + 4);
    union { unsigned int u[4]; bf16x8 v; } r;
    r.u[0] = pack2(x.x, x.y); r.u[1] = pack2(x.z, x.w);
    r.u[2] = pack2(y.x, y.y); r.u[3] = pack2(y.z, y.w);
    return r.v;
}

#define MFMA(a, b, c) __builtin_amdgcn_mfma_f32_16x16x32_bf16(a, b, c, 0, 0, 0)

// ---------------- Kernel A: joint gather + Q/K/VT via MFMA + cand pre-pack ----------
// bx 0..5: which = bx>>1 (0=Q,1=K,2=VT), half = bx&1
// bx == 6: gather cand = emb_loc[posneg[b]] -> bf16 row-major (frag-ready)
__global__ __launch_bounds__(256) void k_stage(
    const int* __restrict__ time_seq, const int* __restrict__ full_seq,
    const int* __restrict__ user, const int* __restrict__ posneg,
    const float* __restrict__ emb_t, const float* __restrict__ emb_u,
    const float* __restrict__ emb_loc,
    const float* __restrict__ Wq, const float* __restrict__ Wk, const float* __restrict__ Wv,
    short* __restrict__ qws, short* __restrict__ kws, short* __restrict__ vtws,
    short* __restrict__ candws)
{
    __shared__ alignas(16) short Jl[64 * 128];   // 16KB
    int b = blockIdx.y;
    int bx = blockIdx.x;
    int tid = threadIdx.x;

    if (bx == 6) {
        // cand gather: 128 rows x 32 float4-units
#pragma unroll
        for (int it = 0; it < 16; ++it) {
            int u = it * 256 + tid;
            int lrow = u >> 5, fq = u & 31;
            int p = posneg[b * MM + lrow];
            float4 v = ((const float4*)(emb_loc + (size_t)p * 128))[fq];
            uint2 pk;
            pk.x = pack2(v.x, v.y);
            pk.y = pack2(v.z, v.w);
            *(uint2*)&candws[((size_t)(b * MM) + lrow) * EE + fq * 4] = pk;
        }
        return;
    }

    int which = bx >> 1;
    int half = bx & 1;
    int m0 = half * 64;
    int l = tid & 63, w = tid >> 6;
    int lr = l & 15, lg = l >> 4;

    // stage joint-half (gather-sum, f32 -> bf16, swizzled)
    int uid = user[b];
    const float4* Eu4 = (const float4*)(emb_u + (size_t)uid * 128);
#pragma unroll
    for (int it = 0; it < 8; ++it) {
        int i4 = it * 256 + tid;          // 2048 float4
        int mm = i4 >> 5;
        int fq = i4 & 31;
        int m = m0 + mm;
        int t = time_seq[b * MM + m];
        int tim = (t - 1) % HOURS + 1;
        int loc = full_seq[b * MM + m];
        float4 a = ((const float4*)(emb_t + (size_t)tim * 128))[fq];
        float4 c = ((const float4*)(emb_loc + (size_t)loc * 128))[fq];
        float4 u = Eu4[fq];
        uint2 pk;
        pk.x = pack2(a.x + c.x + u.x, a.y + c.y + u.y);
        pk.y = pack2(a.z + c.z + u.z, a.w + c.w + u.w);
        *(uint2*)&Jl[swz8(mm, fq >> 1) + (fq & 1) * 4] = pk;
    }
    __syncthreads();

    if (which < 2) {
        const float* W = which ? Wk : Wq;
        short* outp = which ? kws : qws;
        bf16x8 af[2][4];
#pragma unroll
        for (int nt = 0; nt < 2; ++nt) {
            int n = (2 * w + nt) * 16 + lr;
#pragma unroll
            for (int kf = 0; kf < 4; ++kf)
                af[nt][kf] = load_w_frag(W + (size_t)n * 128 + kf * 32 + lg * 8);
        }
        f32x4 acc[2][4];
#pragma unroll
        for (int nt = 0; nt < 2; ++nt)
#pragma unroll
            for (int mt = 0; mt < 4; ++mt) acc[nt][mt] = (f32x4){0.f, 0.f, 0.f, 0.f};
#pragma unroll
        for (int mt = 0; mt < 4; ++mt) {
            bf16x8 bf[4];
#pragma unroll
            for (int kf = 0; kf < 4; ++kf)
                bf[kf] = *(const bf16x8*)&Jl[swz8(mt * 16 + lr, kf * 4 + lg)];
#pragma unroll
            for (int nt = 0; nt < 2; ++nt)
#pragma unroll
                for (int kf = 0; kf < 4; ++kf)
                    acc[nt][mt] = MFMA(af[nt][kf], bf[kf], acc[nt][mt]);
        }
#pragma unroll
        for (int nt = 0; nt < 2; ++nt)
#pragma unroll
            for (int mt = 0; mt < 4; ++mt) {
                int mg = m0 + mt * 16 + lr;
                int n0 = (2 * w + nt) * 16 + lg * 4;
                uint2 pk;
                pk.x = pack2(acc[nt][mt][0], acc[nt][mt][1]);
                pk.y = pack2(acc[nt][mt][2], acc[nt][mt][3]);
                *(uint2*)&outp[(size_t)(b * MM + mg) * EE + n0] = pk;
            }
    } else {
        bf16x8 bfr[2][4];
#pragma unroll
        for (int nt = 0; nt < 2; ++nt) {
            int n = (2 * w + nt) * 16 + lr;
#pragma unroll
            for (int kf = 0; kf < 4; ++kf)
                bfr[nt][kf] = load_w_frag(Wv + (size_t)n * 128 + kf * 32 + lg * 8);
        }
        f32x4 acc[4][2];
#pragma unroll
        for (int mt = 0; mt < 4; ++mt)
#pragma unroll
            for (int nt = 0; nt < 2; ++nt) acc[mt][nt] = (f32x4){0.f, 0.f, 0.f, 0.f};
#pragma unroll
        for (int mt = 0; mt < 4; ++mt) {
            bf16x8 af[4];
#pragma unroll
            for (int kf = 0; kf < 4; ++kf)
                af[kf] = *(const bf16x8*)&Jl[swz8(mt * 16 + lr, kf * 4 + lg)];
#pragma unroll
            for (int nt = 0; nt < 2; ++nt)
#pragma unroll
                for (int kf = 0; kf < 4; ++kf)
                    acc[mt][nt] = MFMA(af[kf], bfr[nt][kf], acc[mt][nt]);
        }
#pragma unroll
        for (int mt = 0; mt < 4; ++mt)
#pragma unroll
            for (int nt = 0; nt < 2; ++nt) {
                int ng = (2 * w + nt) * 16 + lr;
                int mp = m0 + mt * 16 + lg * 4;
                uint2 pk;
                pk.x = pack2(acc[mt][nt][0], acc[mt][nt][1]);
                pk.y = pack2(acc[mt][nt][2], acc[mt][nt][3]);
                *(uint2*)&vtws[(size_t)(b * MM + ng) * MM + mp] = pk;
            }
    }
}

// ---------------- Kernel B: fused attention + final contraction -------------------
// block = (b, chunk of 16 i/m rows). sa stays in LDS; partial out via atomicAdd.
__global__ __launch_bounds__(256) void k_af(
    const short* __restrict__ qws, const short* __restrict__ kws,
    const short* __restrict__ vtws, const short* __restrict__ candws,
    const float* __restrict__ mat1, const float* __restrict__ mat2,
    const float* __restrict__ vecg, const int* __restrict__ traj_len,
    const float* __restrict__ esl, const float* __restrict__ esu,
    const float* __restrict__ etl, const float* __restrict__ etu,
    float* __restrict__ outp)
{
    __shared__ alignas(16) float Sf[16 * 132];   // 8448B
    __shared__ alignas(16) short Pl[16 * 128];   // 4KB
    __shared__ alignas(16) short SAl[16 * 128];  // 4KB
    __shared__ float coef[8];
    __shared__ float tms[16], bsv[16];

    int b = blockIdx.y;
    int chunk = blockIdx.x;
    int i0 = chunk * 16;
    int tid = threadIdx.x;
    int l = tid & 63, w = tid >> 6;
    int lr = l & 15, lg = l >> 4;
    int tl = traj_len[b];

    // coefs: wave w computes table sums 2w, 2w+1
    {
        const float* tb[4] = {esl, esu, etl, etu};
#pragma unroll
        for (int s = 0; s < 2; ++s) {
            int c = 2 * w + s;
            const float* t = tb[c >> 1];
            float v = t[(c & 1) * 128 + l] + t[(c & 1) * 128 + 64 + l];
#pragma unroll
            for (int off = 32; off >= 1; off >>= 1) v += __shfl_xor(v, off, 64);
            if (l == 0) coef[c] = v;
        }
    }
    // Q A-frags direct from global
    bf16x8 qf[4];
#pragma unroll
    for (int kf = 0; kf < 4; ++kf)
        qf[kf] = *(const bf16x8*)&qws[(size_t)(b * MM + i0 + lr) * EE + kf * 32 + lg * 8];

    // QK^T: wave w covers j-tiles {2w, 2w+1}; K B-frags direct from global
#pragma unroll
    for (int t2 = 0; t2 < 2; ++t2) {
        int jt = 2 * w + t2;
        f32x4 acc = (f32x4){0.f, 0.f, 0.f, 0.f};
#pragma unroll
        for (int kf = 0; kf < 4; ++kf) {
            bf16x8 bf = *(const bf16x8*)&kws[(size_t)(b * MM + jt * 16 + lr) * EE + kf * 32 + lg * 8];
            acc = MFMA(qf[kf], bf, acc);
        }
#pragma unroll
        for (int r = 0; r < 4; ++r)
            Sf[(lg * 4 + r) * 132 + jt * 16 + lr] = acc[r];
    }
    __syncthreads();

    // softmax: thread = (row r16, 8-col chunk u); also tms/bsv for the chunk's 16 m
    {
        int r16 = tid >> 4, u = tid & 15;
        int j0 = u * 8;
        int i = i0 + r16;
        int mi = (i < tl) ? 1 : 0;
        float c0_1 = coef[1] + coef[5];
        float c1_1 = (coef[3] - coef[1]) * 0.01f;
        float c2_1 = (coef[7] - coef[5]) * 0.01f;
        float c0_0 = coef[0] + coef[4];
        float c1_0 = (coef[2] - coef[0]) * 0.01f;
        float c2_0 = (coef[6] - coef[4]) * 0.01f;
        const float* sb = &Sf[r16 * 132 + j0];
        float4 s01 = *(const float4*)sb;
        float4 s23 = *(const float4*)(sb + 4);
        float sv[8] = {s01.x, s01.y, s01.z, s01.w, s23.x, s23.y, s23.z, s23.w};
        const float4* m14 = (const float4*)(mat1 + ((size_t)(b * MM + i) * MM + j0) * 2);
        float4 d0 = m14[0], d1 = m14[1], d2 = m14[2], d3 = m14[3];
        float ds[8] = {d0.x, d0.z, d1.x, d1.z, d2.x, d2.z, d3.x, d3.z};
        float dt[8] = {d0.y, d0.w, d1.y, d1.w, d2.y, d2.w, d3.y, d3.w};
        float lgv[8];
        int mk[8];
#pragma unroll
        for (int jj = 0; jj < 8; ++jj) {
            int j = j0 + jj;
            mk[jj] = mi & ((j < tl) ? 1 : 0);
            float cc0 = mk[jj] ? c0_1 : c0_0;
            float cc1 = mk[jj] ? c1_1 : c1_0;
            float cc2 = mk[jj] ? c2_1 : c2_0;
            lgv[jj] = sv[jj] + cc0 + cc1 * ds[jj] + cc2 * dt[jj];
        }
        float mx = lgv[0];
#pragma unroll
        for (int jj = 1; jj < 8; ++jj) mx = fmaxf(mx, lgv[jj]);
#pragma unroll
        for (int off = 8; off >= 1; off >>= 1) mx = fmaxf(mx, __shfl_xor(mx, off, 64));
        float ee[8], sum = 0.f;
#pragma unroll
        for (int jj = 0; jj < 8; ++jj) { ee[jj] = __expf(lgv[jj] - mx); sum += ee[jj]; }
#pragma unroll
        for (int off = 8; off >= 1; off >>= 1) sum += __shfl_xor(sum, off, 64);
        float inv = 1.0f / sum;
        uint4 pk;
        pk.x = pack2(ee[0] * inv * mk[0], ee[1] * inv * mk[1]);
        pk.y = pack2(ee[2] * inv * mk[2], ee[3] * inv * mk[3]);
        pk.z = pack2(ee[4] * inv * mk[4], ee[5] * inv * mk[5]);
        pk.w = pack2(ee[6] * inv * mk[6], ee[7] * inv * mk[7]);
        *(uint4*)&Pl[swz8(r16, u)] = pk;
    }
    if (tid < 16) {
        int mg = i0 + tid;
        int vv = (mg < tl) ? 1 : 0;
        float ssl = vv ? coef[1] : coef[0];
        float ssu = vv ? coef[3] : coef[2];
        float stl = vv ? coef[5] : coef[4];
        float stu = vv ? coef[7] : coef[6];
        tms[tid] = ssl + stl + (stu - stl) * 0.01f * vecg[b * MM + mg];
        bsv[tid] = (ssu - ssl) * 0.01f;
    }
    __syncthreads();

    // PV: sa^T = VT (.) P^T ; VT A-frags direct from global; D[e][i] -> SAl[i][e]
    {
        bf16x8 bp[4];
#pragma unroll
        for (int kf = 0; kf < 4; ++kf)
            bp[kf] = *(const bf16x8*)&Pl[swz8(lr, kf * 4 + lg)];
#pragma unroll
        for (int t2 = 0; t2 < 2; ++t2) {
            int et = 2 * w + t2;
            f32x4 acc = (f32x4){0.f, 0.f, 0.f, 0.f};
#pragma unroll
            for (int kf = 0; kf < 4; ++kf) {
                bf16x8 af = *(const bf16x8*)&vtws[(size_t)(b * MM + et * 16 + lr) * MM + kf * 32 + lg * 8];
                acc = MFMA(af, bp[kf], acc);
            }
            int e0 = et * 16 + lg * 4;
            uint2 pk;
            pk.x = pack2(acc[0], acc[1]);
            pk.y = pack2(acc[2], acc[3]);
            *(uint2*)&SAl[swz8(lr, e0 >> 3) + (e0 & 7)] = pk;
        }
    }
    __syncthreads();

    // G^T[m][l] = sa_m . cand_l ; epilogue: out[b,l] += sum_m G * (tms + bsv*mat2)
    {
        bf16x8 saf[4];
#pragma unroll
        for (int kf = 0; kf < 4; ++kf)
            saf[kf] = *(const bf16x8*)&SAl[swz8(lr, kf * 4 + lg)];
#pragma unroll
        for (int t2 = 0; t2 < 2; ++t2) {
            int lt = 2 * w + t2;
            f32x4 acc = (f32x4){0.f, 0.f, 0.f, 0.f};
#pragma unroll
            for (int kf = 0; kf < 4; ++kf) {
                bf16x8 cf = *(const bf16x8*)&candws[(size_t)(b * MM + lt * 16 + lr) * EE + kf * 32 + lg * 8];
                acc = MFMA(saf[kf], cf, acc);
            }
            int lG = lt * 16 + lr;
            float val = 0.f;
#pragma unroll
            for (int r = 0; r < 4; ++r) {
                int m = lg * 4 + r;
                int mg = i0 + m;
                float w2 = tms[m] + bsv[m] * mat2[(size_t)(b * MM + mg) * MM + lG];
                val += acc[r] * w2;
            }
            // reduce over lg groups (bits 4,5 of lane)
            val += __shfl_xor(val, 16, 64);
            val += __shfl_xor(val, 32, 64);
            if (lg == 0)
                atomicAdd(&outp[b * MM + lG], val);
        }
    }
}

extern "C" void kernel_launch(void* const* d_in, const int* in_sizes, int n_in,
                              void* d_out, int out_size, void* d_ws, size_t ws_size,
                              hipStream_t stream) {
    const int* full_seq = (const int*)d_in[0];
    const int* time_seq = (const int*)d_in[1];
    const int* user     = (const int*)d_in[2];
    const int* posneg   = (const int*)d_in[3];
    const int* traj_len = (const int*)d_in[4];
    const float* mat1   = (const float*)d_in[5];
    const float* mat2   = (const float*)d_in[6];
    const float* vec    = (const float*)d_in[7];
    const float* emb_t  = (const float*)d_in[8];
    const float* emb_u  = (const float*)d_in[9];
    const float* emb_loc= (const float*)d_in[10];
    const float* emb_sl = (const float*)d_in[11];
    const float* emb_su = (const float*)d_in[12];
    const float* emb_tl = (const float*)d_in[13];
    const float* emb_tu = (const float*)d_in[14];
    const float* Wq     = (const float*)d_in[15];
    const float* Wk     = (const float*)d_in[16];
    const float* Wv     = (const float*)d_in[17];

    short* qws   = (short*)d_ws;
    short* kws   = qws + (size_t)NB * MM * EE;
    short* vtws  = kws + (size_t)NB * MM * EE;
    short* candws= vtws + (size_t)NB * MM * EE;

    hipMemsetAsync(d_out, 0, (size_t)out_size * sizeof(float), stream);
    k_stage<<<dim3(7, 32), 256, 0, stream>>>(time_seq, full_seq, user, posneg,
                                             emb_t, emb_u, emb_loc,
                                             Wq, Wk, Wv, qws, kws, vtws, candws);
    k_af<<<dim3(8, 32), 256, 0, stream>>>(qws, kws, vtws, candws, mat1, mat2, vec,
                                          traj_len, emb_sl, emb_su, emb_tl, emb_tu,
                                          (float*)d_out);
}

// Round 6
// 25.802 us; speedup vs baseline: 1.0567x; 1.0567x over previous
//
#include <hip/hip_runtime.h>
#include <hip/hip_bf16.h>

#define HOURS 24
#define MM 128
#define EE 128
#define PS 136   // padded short-stride for P/CV rows (272B, 16B-aligned)

typedef short bf16x8 __attribute__((ext_vector_type(8)));
typedef float f32x4 __attribute__((ext_vector_type(4)));

__device__ __forceinline__ unsigned short f2bfu(float f) {
    __hip_bfloat16 h = __float2bfloat16(f);
    return __builtin_bit_cast(unsigned short, h);
}
__device__ __forceinline__ float bfu2f(unsigned short u) {
    unsigned int x = ((unsigned int)u) << 16;
    return __builtin_bit_cast(float, x);
}
__device__ __forceinline__ unsigned int pack2(float a, float b) {
    return (unsigned int)f2bfu(a) | ((unsigned int)f2bfu(b) << 16);
}
// swizzled short-index of 16B unit `unit` in row `row` of a [*][128] bf16 tile
__device__ __forceinline__ int swz8(int row, int unit) {
    return row * 128 + (((unit ^ (row & 7)) & 15) << 3);
}
// load 8 consecutive f32 from global, convert to bf16x8 fragment
__device__ __forceinline__ bf16x8 load_w_frag(const float* base) {
    float4 x = *(const float4*)base;
    float4 y = *(const float4*)(base + 4);
    union { unsigned int u[4]; bf16x8 v; } r;
    r.u[0] = pack2(x.x, x.y); r.u[1] = pack2(x.z, x.w);
    r.u[2] = pack2(y.x, y.y); r.u[3] = pack2(y.z, y.w);
    return r.v;
}

#define MFMA(a, b, c) __builtin_amdgcn_mfma_f32_16x16x32_bf16(a, b, c, 0, 0, 0)

// ONE dispatch. block = (b, lc): 16 candidate l's per block, 256 blocks, 256 thr.
// P0: coefs + gather full J + cand chunk
// P1: tms/bsv + K,V,Q GEMMs (full 128x128 each) into LDS
// P2: CV = cand.V^T (hi/lo bf16) ; QK^T with in-register softmax -> P (LDS)
// P3: G = CV.P^T ; epilogue sum over m ; direct store of 16 outputs
__global__ __launch_bounds__(256) void k_one(
    const int* __restrict__ full_seq, const int* __restrict__ time_seq,
    const int* __restrict__ user, const int* __restrict__ posneg,
    const int* __restrict__ traj_len,
    const float* __restrict__ mat1, const float* __restrict__ mat2,
    const float* __restrict__ vecg,
    const float* __restrict__ emb_t, const float* __restrict__ emb_u,
    const float* __restrict__ emb_loc,
    const float* __restrict__ esl, const float* __restrict__ esu,
    const float* __restrict__ etl, const float* __restrict__ etu,
    const float* __restrict__ Wq, const float* __restrict__ Wk,
    const float* __restrict__ Wv,
    float* __restrict__ outp)
{
    __shared__ alignas(16) short U0[MM * PS];     // J (swz8) -> P (stride PS)  34816B
    __shared__ alignas(16) short Kl[MM * EE];     // 32KB
    __shared__ alignas(16) short Vl[MM * EE];     // 32KB
    __shared__ alignas(16) short Ql[MM * EE];     // 32KB
    __shared__ alignas(16) short CAl[16 * EE];    // 4KB
    __shared__ alignas(16) short CVh[16 * PS];    // 4352B
    __shared__ alignas(16) short CVm[16 * PS];    // 4352B
    __shared__ float tms[MM], bsv[MM], coef[8], PART[4][16];

    const int b = blockIdx.y, lc = blockIdx.x;
    const int l0g = lc * 16;
    const int tid = threadIdx.x;
    const int w = tid >> 6, l = tid & 63;
    const int lr = l & 15, lg = l >> 4;
    const int tl = traj_len[b];

    // ---------------- P0: coefs + gather J (full) + cand chunk ----------------
    {
        const float* tb4[4] = {esl, esu, etl, etu};
#pragma unroll
        for (int s = 0; s < 2; ++s) {
            int c = 2 * w + s;
            const float* t = tb4[c >> 1];
            float v = t[(c & 1) * 128 + l] + t[(c & 1) * 128 + 64 + l];
#pragma unroll
            for (int off = 32; off >= 1; off >>= 1) v += __shfl_xor(v, off, 64);
            if (l == 0) coef[c] = v;
        }
    }
    {
        int uid = user[b];
        const float4* Eu4 = (const float4*)(emb_u + (size_t)uid * 128);
#pragma unroll
        for (int it = 0; it < 16; ++it) {
            int i4 = it * 256 + tid;          // 4096 float4 units (128 rows x 32)
            int mm = i4 >> 5, fq = i4 & 31;
            int t = time_seq[b * MM + mm];
            int tim = (t - 1) % HOURS + 1;
            int loc = full_seq[b * MM + mm];
            float4 a = ((const float4*)(emb_t + (size_t)tim * 128))[fq];
            float4 c = ((const float4*)(emb_loc + (size_t)loc * 128))[fq];
            float4 u = Eu4[fq];
            uint2 pk;
            pk.x = pack2(a.x + c.x + u.x, a.y + c.y + u.y);
            pk.y = pack2(a.z + c.z + u.z, a.w + c.w + u.w);
            *(uint2*)&U0[swz8(mm, fq >> 1) + (fq & 1) * 4] = pk;
        }
#pragma unroll
        for (int it = 0; it < 2; ++it) {
            int u = it * 256 + tid;           // 512 units (16 rows x 32)
            int row = u >> 5, fq = u & 31;
            int p = posneg[b * MM + l0g + row];
            float4 v = ((const float4*)(emb_loc + (size_t)p * 128))[fq];
            uint2 pk;
            pk.x = pack2(v.x, v.y);
            pk.y = pack2(v.z, v.w);
            *(uint2*)&CAl[swz8(row, fq >> 1) + (fq & 1) * 4] = pk;
        }
    }
    __syncthreads();

    // ---------------- P1: tms/bsv + K,V,Q GEMMs into LDS ----------------
    if (tid < 128) {
        int vv = (tid < tl) ? 1 : 0;
        float ssl = vv ? coef[1] : coef[0];
        float ssu = vv ? coef[3] : coef[2];
        float stl = vv ? coef[5] : coef[4];
        float stu = vv ? coef[7] : coef[6];
        tms[tid] = ssl + stl + (stu - stl) * 0.01f * vecg[b * MM + tid];
        bsv[tid] = (ssu - ssl) * 0.01f;
    }
    {
        const float* Ws[3] = {Wk, Wv, Wq};
        short* Xs[3] = {Kl, Vl, Ql};
#pragma unroll
        for (int g = 0; g < 3; ++g) {
            const float* W = Ws[g];
            short* X = Xs[g];
            bf16x8 af[2][4];
#pragma unroll
            for (int nt = 0; nt < 2; ++nt) {
                int n = (2 * w + nt) * 16 + lr;
#pragma unroll
                for (int kf = 0; kf < 4; ++kf)
                    af[nt][kf] = load_w_frag(W + (size_t)n * 128 + kf * 32 + lg * 8);
            }
#pragma unroll
            for (int mt = 0; mt < 8; ++mt) {
                bf16x8 bj[4];
#pragma unroll
                for (int kf = 0; kf < 4; ++kf)
                    bj[kf] = *(const bf16x8*)&U0[swz8(mt * 16 + lr, kf * 4 + lg)];
                f32x4 a0 = (f32x4){0.f,0.f,0.f,0.f}, a1 = (f32x4){0.f,0.f,0.f,0.f};
#pragma unroll
                for (int kf = 0; kf < 4; ++kf) {
                    a0 = MFMA(af[0][kf], bj[kf], a0);
                    a1 = MFMA(af[1][kf], bj[kf], a1);
                }
                int m = mt * 16 + lr;
#pragma unroll
                for (int nt = 0; nt < 2; ++nt) {
                    f32x4 av = nt ? a1 : a0;
                    int n0 = (2 * w + nt) * 16 + lg * 4;
                    uint2 pk;
                    pk.x = pack2(av[0], av[1]);
                    pk.y = pack2(av[2], av[3]);
                    *(uint2*)&X[swz8(m, n0 >> 3) + (n0 & 7)] = pk;
                }
            }
        }
    }
    __syncthreads();

    // ---------------- P2: CV (hi/lo) + QK^T + in-register softmax -> P --------
    {
        bf16x8 ca[4];
#pragma unroll
        for (int kf = 0; kf < 4; ++kf)
            ca[kf] = *(const bf16x8*)&CAl[swz8(lr, kf * 4 + lg)];
#pragma unroll
        for (int t2 = 0; t2 < 2; ++t2) {
            int jt = 2 * w + t2;
            f32x4 acc = (f32x4){0.f,0.f,0.f,0.f};
#pragma unroll
            for (int kf = 0; kf < 4; ++kf) {
                bf16x8 bv = *(const bf16x8*)&Vl[swz8(jt * 16 + lr, kf * 4 + lg)];
                acc = MFMA(ca[kf], bv, acc);
            }
#pragma unroll
            for (int r = 0; r < 4; ++r) {
                float f = acc[r];
                unsigned short h = f2bfu(f);
                float rem = f - bfu2f(h);
                CVh[(4 * lg + r) * PS + jt * 16 + lr] = (short)h;
                CVm[(4 * lg + r) * PS + jt * 16 + lr] = (short)f2bfu(rem);
            }
        }
    }
    {
        float c0_1 = coef[1] + coef[5];
        float c1_1 = (coef[3] - coef[1]) * 0.01f;
        float c2_1 = (coef[7] - coef[5]) * 0.01f;
        float c0_0 = coef[0] + coef[4];
        float c1_0 = (coef[2] - coef[0]) * 0.01f;
        float c2_0 = (coef[6] - coef[4]) * 0.01f;
#pragma unroll
        for (int t2 = 0; t2 < 2; ++t2) {
            int it = 2 * w + t2;
            bf16x8 qf[4];
#pragma unroll
            for (int kf = 0; kf < 4; ++kf)
                qf[kf] = *(const bf16x8*)&Ql[swz8(it * 16 + lr, kf * 4 + lg)];
            f32x4 acc[8];
#pragma unroll
            for (int jt = 0; jt < 8; ++jt) acc[jt] = (f32x4){0.f,0.f,0.f,0.f};
#pragma unroll
            for (int jt = 0; jt < 8; ++jt) {
#pragma unroll
                for (int kf = 0; kf < 4; ++kf) {
                    bf16x8 bk = *(const bf16x8*)&Kl[swz8(jt * 16 + lr, kf * 4 + lg)];
                    acc[jt] = MFMA(qf[kf], bk, acc[jt]);
                }
            }
#pragma unroll
            for (int r = 0; r < 4; ++r) {
                int ig = it * 16 + 4 * lg + r;      // S row i (0..127)
                int mi = (ig < tl) ? 1 : 0;
                float lgv[8];
                int mk[8];
#pragma unroll
                for (int jt = 0; jt < 8; ++jt) {
                    int j = jt * 16 + lr;           // S col j
                    mk[jt] = mi & ((j < tl) ? 1 : 0);
                    float2 d = *(const float2*)&mat1[((size_t)(b * MM + ig) * MM + j) * 2];
                    float cc0 = mk[jt] ? c0_1 : c0_0;
                    float cc1 = mk[jt] ? c1_1 : c1_0;
                    float cc2 = mk[jt] ? c2_1 : c2_0;
                    lgv[jt] = acc[jt][r] + cc0 + cc1 * d.x + cc2 * d.y;
                }
                float mx = lgv[0];
#pragma unroll
                for (int jt = 1; jt < 8; ++jt) mx = fmaxf(mx, lgv[jt]);
#pragma unroll
                for (int off = 8; off >= 1; off >>= 1) mx = fmaxf(mx, __shfl_xor(mx, off, 64));
                float ee[8], sum = 0.f;
#pragma unroll
                for (int jt = 0; jt < 8; ++jt) { ee[jt] = __expf(lgv[jt] - mx); sum += ee[jt]; }
#pragma unroll
                for (int off = 8; off >= 1; off >>= 1) sum += __shfl_xor(sum, off, 64);
                float inv = 1.0f / sum;
#pragma unroll
                for (int jt = 0; jt < 8; ++jt)
                    U0[ig * PS + jt * 16 + lr] = (short)f2bfu(ee[jt] * inv * (float)mk[jt]);
            }
        }
    }
    __syncthreads();

    // ---------------- P3: G = CV . P^T ; epilogue ; direct store --------------
    {
        bf16x8 cah[4], cam[4];
#pragma unroll
        for (int kf = 0; kf < 4; ++kf) {
            cah[kf] = *(const bf16x8*)&CVh[lr * PS + kf * 32 + lg * 8];
            cam[kf] = *(const bf16x8*)&CVm[lr * PS + kf * 32 + lg * 8];
        }
        float val[4] = {0.f, 0.f, 0.f, 0.f};
#pragma unroll
        for (int t2 = 0; t2 < 2; ++t2) {
            int mt = 2 * w + t2;
            f32x4 acc = (f32x4){0.f,0.f,0.f,0.f};
#pragma unroll
            for (int kf = 0; kf < 4; ++kf) {
                bf16x8 bp = *(const bf16x8*)&U0[(mt * 16 + lr) * PS + kf * 32 + lg * 8];
                acc = MFMA(cah[kf], bp, acc);
                acc = MFMA(cam[kf], bp, acc);
            }
            int m = mt * 16 + lr;
            float4 m2 = *(const float4*)&mat2[(size_t)(b * MM + m) * MM + l0g + lg * 4];
            float wt = tms[m], wb = bsv[m];
            val[0] += acc[0] * (wt + wb * m2.x);
            val[1] += acc[1] * (wt + wb * m2.y);
            val[2] += acc[2] * (wt + wb * m2.z);
            val[3] += acc[3] * (wt + wb * m2.w);
        }
#pragma unroll
        for (int r = 0; r < 4; ++r) {
            float v = val[r];
            v += __shfl_xor(v, 1, 64);
            v += __shfl_xor(v, 2, 64);
            v += __shfl_xor(v, 4, 64);
            v += __shfl_xor(v, 8, 64);
            if (lr == 0) PART[w][lg * 4 + r] = v;
        }
    }
    __syncthreads();
    if (tid < 16)
        outp[b * MM + l0g + tid] = PART[0][tid] + PART[1][tid] + PART[2][tid] + PART[3][tid];
}

extern "C" void kernel_launch(void* const* d_in, const int* in_sizes, int n_in,
                              void* d_out, int out_size, void* d_ws, size_t ws_size,
                              hipStream_t stream) {
    const int* full_seq = (const int*)d_in[0];
    const int* time_seq = (const int*)d_in[1];
    const int* user     = (const int*)d_in[2];
    const int* posneg   = (const int*)d_in[3];
    const int* traj_len = (const int*)d_in[4];
    const float* mat1   = (const float*)d_in[5];
    const float* mat2   = (const float*)d_in[6];
    const float* vec    = (const float*)d_in[7];
    const float* emb_t  = (const float*)d_in[8];
    const float* emb_u  = (const float*)d_in[9];
    const float* emb_loc= (const float*)d_in[10];
    const float* emb_sl = (const float*)d_in[11];
    const float* emb_su = (const float*)d_in[12];
    const float* emb_tl = (const float*)d_in[13];
    const float* emb_tu = (const float*)d_in[14];
    const float* Wq     = (const float*)d_in[15];
    const float* Wk     = (const float*)d_in[16];
    const float* Wv     = (const float*)d_in[17];

    k_one<<<dim3(8, 32), 256, 0, stream>>>(full_seq, time_seq, user, posneg, traj_len,
                                           mat1, mat2, vec, emb_t, emb_u, emb_loc,
                                           emb_sl, emb_su, emb_tl, emb_tu,
                                           Wq, Wk, Wv, (float*)d_out);
}